// Round 4
// baseline (212.557 us; speedup 1.0000x reference)
//
#include <hip/hip_runtime.h>
#include <hip/hip_bf16.h>
#include <cstdint>
#include <cstddef>

#define NN 1024
#define FF 256

typedef __attribute__((ext_vector_type(8))) short bf16x8;
typedef __attribute__((ext_vector_type(4))) float f32x4;

__device__ __forceinline__ short f2bf(float x) {
  unsigned int u = __float_as_uint(x);
  u = (u + 0x7fffu + ((u >> 16) & 1u)) >> 16;   // RNE
  return (short)u;
}

// ---- PT tiled layout (all bf16 matrices) ----
// 16-row x 32-k tiles (512 elems) ordered so that a wave load at
// (tile_base + lane*8 elems) IS the MFMA fragment:
//   lane -> (row = lane&15, k = (lane>>4)*8 + j)
// elem-in-tile(row,k) = ((k&31)>>3)*128 + (row&15)*8 + (k&7)
// HT_tiled   (F x 1024/bw): bw*F*1024 + (f>>4)*16384 + (node>>5)*512 + pt(f,node)
// Anorm_tiled(1024x1024/bw): bw*2^20  + (r>>4)*16384 + (k>>5)*512    + pt(r,k)
// WT_tiled   (F_OUT x 256) : (fo>>4)*4096 + (k>>5)*512               + pt(fo,k)

// ---------------- d = (rowsum(adj)+1)^-1/2, one wave per row ----------------
__global__ __launch_bounds__(256)
void compute_dinv(const float* __restrict__ adj, float* __restrict__ dinv) {
  int wid = threadIdx.x >> 6, lane = threadIdx.x & 63;
  int row = (blockIdx.x << 2) + wid;           // 0..32767
  const float4* r = (const float4*)(adj + (size_t)row * NN);
  float s = 0.f;
  #pragma unroll
  for (int i = 0; i < 4; i++) {
    float4 v = r[lane + (i << 6)];
    s += (v.x + v.y) + (v.z + v.w);
  }
  #pragma unroll
  for (int off = 32; off > 0; off >>= 1) s += __shfl_down(s, off, 64);
  if (lane == 0) dinv[row] = rsqrtf(s + 1.0f);
}

// ---- Anorm_tiled[bw](r,k) = (adj + I) * dr * dk, PT format -----------------
__global__ __launch_bounds__(256)
void normalize_adj(const float* __restrict__ adj, const float* __restrict__ dinv,
                   short* __restrict__ Anorm) {
  int gid = blockIdx.x;                        // bw*1024 + r
  int bw = gid >> 10, r = gid & 1023;
  float dr = dinv[gid];
  const float* src = adj + (size_t)gid * NN;
  const float* dv  = dinv + (bw << 10);
  int k = threadIdx.x << 2;
  float4 a = *(const float4*)(src + k);
  float4 d = *(const float4*)(dv + k);
  float v0 = (a.x + ((r == k + 0) ? 1.f : 0.f)) * dr * d.x;
  float v1 = (a.y + ((r == k + 1) ? 1.f : 0.f)) * dr * d.y;
  float v2 = (a.z + ((r == k + 2) ? 1.f : 0.f)) * dr * d.z;
  float v3 = (a.w + ((r == k + 3) ? 1.f : 0.f)) * dr * d.w;
  ushort4 o;
  o.x = (unsigned short)f2bf(v0); o.y = (unsigned short)f2bf(v1);
  o.z = (unsigned short)f2bf(v2); o.w = (unsigned short)f2bf(v3);
  size_t e = ((size_t)bw << 20) + ((size_t)(r >> 4) << 14) + ((k >> 5) << 9)
           + (((k & 31) >> 3) << 7) + ((r & 15) << 3) + (k & 7);
  *(ushort4*)(Anorm + e) = o;
}

// ---- X [bw][n][256] fp32 -> HT_tiled[bw](f, node) bf16 ---------------------
__global__ __launch_bounds__(256)
void transpose_x(const float* __restrict__ X, short* __restrict__ XT) {
  __shared__ short T[64][72];
  int bwo = blockIdx.z;
  int n0 = blockIdx.x << 6, f0 = blockIdx.y << 6;
  int t = threadIdx.x;
  {
    int n = t >> 2, fc = (t & 3) << 4;
    const float* src = X + (((size_t)bwo * NN + n0 + n) * FF) + f0 + fc;
    #pragma unroll
    for (int i = 0; i < 4; i++) {
      float4 v = ((const float4*)src)[i];
      ushort4 p;
      p.x = (unsigned short)f2bf(v.x); p.y = (unsigned short)f2bf(v.y);
      p.z = (unsigned short)f2bf(v.z); p.w = (unsigned short)f2bf(v.w);
      *(ushort4*)&T[n][fc + (i << 2)] = p;
    }
  }
  __syncthreads();
  {
    int f = t >> 2, nc = (t & 3) << 4;       // 16 consecutive nodes at fixed f
    int fg = f0 + f, ng = n0 + nc;
    short tmp[16];
    #pragma unroll
    for (int i = 0; i < 16; i++) tmp[i] = T[nc + i][f];
    size_t e0 = ((size_t)bwo << 18) + ((size_t)(fg >> 4) << 14) + ((ng >> 5) << 9)
              + (((ng & 31) >> 3) << 7) + ((fg & 15) << 3);
    *(int4*)(XT + e0)       = *(int4*)&tmp[0];
    *(int4*)(XT + e0 + 128) = *(int4*)&tmp[8];
  }
}

// ---- W [256][FO] fp32 -> WT_tiled(fo, fi) bf16 -----------------------------
__global__ __launch_bounds__(256)
void transpose_w(const float* __restrict__ W, short* __restrict__ WT, int FO) {
  int idx = blockIdx.x * 256 + threadIdx.x;
  if (idx >= FO * 256) return;
  int fo = idx >> 8, fi = idx & 255;
  size_t e = (size_t)((fo >> 4) << 12) + ((fi >> 5) << 9)
           + (((fi & 31) >> 3) << 7) + ((fo & 15) << 3) + (fi & 7);
  WT[e] = f2bf(W[fi * FO + fo]);
}

// ---------------- fused layer (flipped orientation) -------------------------
// Grid 512 x 256 thr (4 waves). Block = 64 r x 256 f of aggT = HT . Anorm^T.
// Wave w owns f-slice [w*64, w*64+64). No LDS / no barriers in stage 1:
// register-only depth-2 pipeline, all operand loads 1KB coalesced (PT tiles).
// One syncthreads at agg spill (XOR-swizzled LDS), then stage 2 from L2.
template<int F_OUT, bool FINAL>
__global__ __launch_bounds__(256, 2)
void gcn_layer(const short* __restrict__ Anorm,   // PT tiled
               const short* __restrict__ HTin,    // PT tiled, F=256
               const short* __restrict__ WT,      // PT tiled
               const float* __restrict__ bias,
               short* __restrict__ HTout,         // PT tiled, F_OUT
               float* __restrict__ Out) {         // [32][1024][F_OUT] fp32
  constexpr int NFO = F_OUT / 64;                 // stage-2 n-tiles per wave
  __shared__ short aggL[64 * 272];                // 64 rows x 544 B (16B-aligned)

  int b = blockIdx.x;
  int bw = ((b & 7) << 2) + ((b >> 3) & 3);       // XCD-locality by bw
  int rb = b >> 5;                                // 0..15
  int r0 = rb << 6;

  int tid = threadIdx.x;
  int wid = tid >> 6, lane = tid & 63;
  int l15 = lane & 15, l4 = lane >> 4;

  const short* Hbase = HTin  + ((size_t)bw << 18) + ((size_t)(wid << 2) << 14) + (lane << 3);
  const short* Abase = Anorm + ((size_t)bw << 20) + ((size_t)(rb  << 2) << 14) + (lane << 3);

  f32x4 acc[4][4];
  #pragma unroll
  for (int am = 0; am < 4; am++)
    #pragma unroll
    for (int nf = 0; nf < 4; nf++) acc[am][nf] = f32x4{0.f, 0.f, 0.f, 0.f};

  bf16x8 h0[4][2], b0[4][2], h1[4][2], b1[4][2];

#define LOADT(HB, BB, T)                                                      \
  {                                                                           \
    int kt2 = (T) << 1;                                                       \
    _Pragma("unroll")                                                         \
    for (int am = 0; am < 4; am++) {                                          \
      HB[am][0] = *(const bf16x8*)(Hbase + am * 16384 + (size_t)kt2 * 512);   \
      HB[am][1] = *(const bf16x8*)(Hbase + am * 16384 + (size_t)(kt2 + 1) * 512); \
    }                                                                         \
    _Pragma("unroll")                                                         \
    for (int nf = 0; nf < 4; nf++) {                                          \
      BB[nf][0] = *(const bf16x8*)(Abase + nf * 16384 + (size_t)kt2 * 512);   \
      BB[nf][1] = *(const bf16x8*)(Abase + nf * 16384 + (size_t)(kt2 + 1) * 512); \
    }                                                                         \
  }

#define MFMAT(HB, BB)                                                         \
  _Pragma("unroll")                                                           \
  for (int kt = 0; kt < 2; kt++)                                              \
    _Pragma("unroll")                                                         \
    for (int am = 0; am < 4; am++)                                            \
      _Pragma("unroll")                                                       \
      for (int nf = 0; nf < 4; nf++)                                          \
        acc[am][nf] = __builtin_amdgcn_mfma_f32_16x16x32_bf16(                \
            HB[am][kt], BB[nf][kt], acc[am][nf], 0, 0, 0);

  LOADT(h0, b0, 0);
  LOADT(h1, b1, 1);
  #pragma unroll
  for (int th = 0; th < 8; th++) {
    MFMAT(h0, b0);
    if (th < 7) LOADT(h0, b0, 2 * th + 2);
    MFMAT(h1, b1);
    if (th < 7) LOADT(h1, b1, 2 * th + 3);
  }
#undef LOADT
#undef MFMAT

  // ---- spill aggT -> aggL[r][f] bf16, XOR-swizzled (byte ^= (r&7)<<4) ----
  #pragma unroll
  for (int am = 0; am < 4; am++)
    #pragma unroll
    for (int nf = 0; nf < 4; nf++) {
      int r = (nf << 4) + l15;
      int colB = (wid << 7) + (am << 5) + (l4 << 3);   // f*2 bytes
      int off = (r * 544 + (colB ^ ((r & 7) << 4))) >> 1;
      ushort4 p;
      p.x = (unsigned short)f2bf(acc[am][nf][0]);
      p.y = (unsigned short)f2bf(acc[am][nf][1]);
      p.z = (unsigned short)f2bf(acc[am][nf][2]);
      p.w = (unsigned short)f2bf(acc[am][nf][3]);
      *(ushort4*)(aggL + off) = p;
    }
  __syncthreads();

  // ---- stage 2: out = relu(agg @ W + b), K = 256, W from L2 (PT tiles) ----
  const short* Wbase = WT + ((size_t)(wid * NFO) << 12) + (lane << 3);
  f32x4 acc2[4][NFO];
  #pragma unroll
  for (int am = 0; am < 4; am++)
    #pragma unroll
    for (int nf = 0; nf < NFO; nf++) acc2[am][nf] = f32x4{0.f, 0.f, 0.f, 0.f};

  #pragma unroll
  for (int ks = 0; ks < 8; ks++) {
    bf16x8 af[4];
    #pragma unroll
    for (int am = 0; am < 4; am++) {
      int r = (am << 4) + l15;
      int colB = (ks << 6) + (l4 << 4);
      int off = (r * 544 + (colB ^ ((r & 7) << 4))) >> 1;
      af[am] = *(const bf16x8*)(aggL + off);
    }
    #pragma unroll
    for (int nf = 0; nf < NFO; nf++) {
      bf16x8 wv = *(const bf16x8*)(Wbase + ((size_t)nf << 12) + (ks << 9));
      #pragma unroll
      for (int am = 0; am < 4; am++)
        acc2[am][nf] = __builtin_amdgcn_mfma_f32_16x16x32_bf16(af[am], wv, acc2[am][nf], 0, 0, 0);
    }
  }

  // ---- epilogue: bias + relu + store ----
  #pragma unroll
  for (int am = 0; am < 4; am++) {
    int nloc = (am << 4) + (l4 << 2);                 // node within block (+reg)
    int node = r0 + nloc;
    #pragma unroll
    for (int nf = 0; nf < NFO; nf++) {
      int fo = wid * (F_OUT / 4) + (nf << 4) + l15;
      float bb = bias[fo];
      float v0 = fmaxf(acc2[am][nf][0] + bb, 0.f);
      float v1 = fmaxf(acc2[am][nf][1] + bb, 0.f);
      float v2 = fmaxf(acc2[am][nf][2] + bb, 0.f);
      float v3 = fmaxf(acc2[am][nf][3] + bb, 0.f);
      if (!FINAL) {
        ushort4 p;
        p.x = (unsigned short)f2bf(v0); p.y = (unsigned short)f2bf(v1);
        p.z = (unsigned short)f2bf(v2); p.w = (unsigned short)f2bf(v3);
        size_t e = (size_t)bw * (F_OUT * 1024) + ((size_t)(fo >> 4) << 14)
                 + ((size_t)(node >> 5) << 9) + (((node & 31) >> 3) << 7)
                 + ((fo & 15) << 3) + (node & 7);
        *(ushort4*)(HTout + e) = p;
      } else {
        float* ob = Out + ((size_t)bw * NN + node) * F_OUT + fo;
        ob[0]         = v0;
        ob[F_OUT]     = v1;
        ob[2 * F_OUT] = v2;
        ob[3 * F_OUT] = v3;
      }
    }
  }
}

extern "C" void kernel_launch(void* const* d_in, const int* in_sizes, int n_in,
                              void* d_out, int out_size, void* d_ws, size_t ws_size,
                              hipStream_t stream) {
  const float* X   = (const float*)d_in[0];
  const float* adj = (const float*)d_in[1];
  const float* W1  = (const float*)d_in[2];
  const float* b1  = (const float*)d_in[3];
  const float* W2  = (const float*)d_in[4];
  const float* b2  = (const float*)d_in[5];
  const float* W3  = (const float*)d_in[6];
  const float* b3  = (const float*)d_in[7];
  float* out = (float*)d_out;

  char* ws = (char*)d_ws;
  float* dinv = (float*)ws;                              // 128 KB
  short* WT1  = (short*)(ws + 131072);                   // 128 KB
  short* WT2  = (short*)(ws + 262144);                   // 128 KB
  short* WT3  = (short*)(ws + 393216);                   //  64 KB
  short* bufA = (short*)(ws + 458752);                   //  16 MB
  short* bufB = (short*)(ws + 458752 + 16777216);        //  16 MB
  short* Anorm = (short*)(ws + 458752 + 2 * 16777216);   //  64 MB

  compute_dinv<<<8192, 256, 0, stream>>>(adj, dinv);
  normalize_adj<<<32768, 256, 0, stream>>>(adj, dinv, Anorm);
  transpose_x<<<dim3(16, 4, 32), 256, 0, stream>>>(X, bufA);
  transpose_w<<<256, 256, 0, stream>>>(W1, WT1, 256);
  transpose_w<<<256, 256, 0, stream>>>(W2, WT2, 256);
  transpose_w<<<128, 256, 0, stream>>>(W3, WT3, 128);

  gcn_layer<256, false><<<512, 256, 0, stream>>>(Anorm, bufA, WT1, b1, bufB, nullptr);
  gcn_layer<256, false><<<512, 256, 0, stream>>>(Anorm, bufB, WT2, b2, bufA, nullptr);
  gcn_layer<128, true ><<<512, 256, 0, stream>>>(Anorm, bufA, WT3, b3, nullptr, out);
}

// Round 5
// 177.333 us; speedup vs baseline: 1.1986x; 1.1986x over previous
//
#include <hip/hip_runtime.h>
#include <hip/hip_bf16.h>
#include <cstdint>
#include <cstddef>

#define NN 1024
#define FF 256

typedef __attribute__((ext_vector_type(8))) short bf16x8;
typedef __attribute__((ext_vector_type(4))) float f32x4;

__device__ __forceinline__ short f2bf(float x) {
  unsigned int u = __float_as_uint(x);
  u = (u + 0x7fffu + ((u >> 16) & 1u)) >> 16;   // RNE
  return (short)u;
}

// ---- PT tiled layout (all bf16 matrices) ----
// 16-row x 32-k tiles (512 elems): elem(row,k) = ((k&31)>>3)*128 + (row&15)*8 + (k&7)
// A wave load at (tile_base + lane*8) IS the MFMA fragment:
//   lane -> (row = lane&15, k = (lane>>4)*8 + j)
// Ahat (1024x1024/bw): bw<<20 + (r>>4)<<14 + (k>>5)<<9 + pt(r,k)    [r=row, k=col]
// G    (F x 1024/bw) : bw*F*1024 + (f>>4)<<14 + (n>>5)<<9 + pt(f,n) [f=row, n=node]
// WT   (F_OUT x 256) : (fo>>4)*4096 + (fi>>5)<<9 + pt(fo,fi)

// ---- fused: d = rsqrt(rowsum(adj)+1), Ahat = (adj+I) bf16 PT-tiled ---------
__global__ __launch_bounds__(256)
void dinv_cast(const float* __restrict__ adj, float* __restrict__ dinv,
               short* __restrict__ Ahat) {
  int wid = threadIdx.x >> 6, lane = threadIdx.x & 63;
  int gr = (blockIdx.x << 2) + wid;            // 0..32767
  int bw = gr >> 10, r = gr & 1023;
  const float* src = adj + (size_t)gr * NN;
  short* tbase = Ahat + ((size_t)bw << 20) + ((size_t)(r >> 4) << 14) + ((r & 15) << 3);
  float s = 0.f;
  #pragma unroll
  for (int i = 0; i < 4; i++) {
    int k = (i << 8) + (lane << 2);
    float4 a = *(const float4*)(src + k);
    a.x += (r == k + 0) ? 1.f : 0.f;
    a.y += (r == k + 1) ? 1.f : 0.f;
    a.z += (r == k + 2) ? 1.f : 0.f;
    a.w += (r == k + 3) ? 1.f : 0.f;
    s += (a.x + a.y) + (a.z + a.w);
    ushort4 o;
    o.x = (unsigned short)f2bf(a.x); o.y = (unsigned short)f2bf(a.y);
    o.z = (unsigned short)f2bf(a.z); o.w = (unsigned short)f2bf(a.w);
    int e = ((k >> 5) << 9) + (((k & 31) >> 3) << 7) + (k & 7);
    *(ushort4*)(tbase + e) = o;
  }
  #pragma unroll
  for (int off = 32; off > 0; off >>= 1) s += __shfl_down(s, off, 64);
  if (lane == 0) dinv[gr] = rsqrtf(s);
}

// ---- X [bw][n][256] fp32 -> G1 = d[n]*X, PT(f, n) bf16 ---------------------
__global__ __launch_bounds__(256)
void transpose_x(const float* __restrict__ X, const float* __restrict__ dinv,
                 short* __restrict__ XT) {
  __shared__ short T[64][72];
  int bwo = blockIdx.z;
  int n0 = blockIdx.x << 6, f0 = blockIdx.y << 6;
  int t = threadIdx.x;
  {
    int n = t >> 2, fc = (t & 3) << 4;
    float dn = dinv[(bwo << 10) + n0 + n];
    const float* src = X + (((size_t)bwo * NN + n0 + n) * FF) + f0 + fc;
    #pragma unroll
    for (int i = 0; i < 4; i++) {
      float4 v = ((const float4*)src)[i];
      ushort4 p;
      p.x = (unsigned short)f2bf(v.x * dn); p.y = (unsigned short)f2bf(v.y * dn);
      p.z = (unsigned short)f2bf(v.z * dn); p.w = (unsigned short)f2bf(v.w * dn);
      *(ushort4*)&T[n][fc + (i << 2)] = p;
    }
  }
  __syncthreads();
  {
    int f = t >> 2, nc = (t & 3) << 4;
    int fg = f0 + f, ng = n0 + nc;
    short tmp[16];
    #pragma unroll
    for (int i = 0; i < 16; i++) tmp[i] = T[nc + i][f];
    size_t e0 = ((size_t)bwo << 18) + ((size_t)(fg >> 4) << 14) + ((ng >> 5) << 9)
              + (((ng & 31) >> 3) << 7) + ((fg & 15) << 3);
    *(int4*)(XT + e0)       = *(int4*)&tmp[0];
    *(int4*)(XT + e0 + 128) = *(int4*)&tmp[8];
  }
}

// ---- W [256][FO] fp32 -> WT PT(fo, fi) bf16 --------------------------------
__global__ __launch_bounds__(256)
void transpose_w(const float* __restrict__ W, short* __restrict__ WT, int FO) {
  int idx = blockIdx.x * 256 + threadIdx.x;
  if (idx >= FO * 256) return;
  int fo = idx >> 8, fi = idx & 255;
  size_t e = (size_t)((fo >> 4) << 12) + ((fi >> 5) << 9)
           + (((fi & 31) >> 3) << 7) + ((fo & 15) << 3) + (fi & 7);
  WT[e] = f2bf(W[fi * FO + fo]);
}

// ---------------- fused layer ----------------------------------------------
// Grid 1024 (32 bw x 32 rb), 256 thr (4 waves), 4 blocks/CU (4 waves/SIMD).
// Block tile: 32 rows x 256 f. Wave: f-slice 64. Stage 1 register-only,
// depth-2 pipeline, no barriers. g-form: acc = Ahat @ g; agg = d[r]*acc.
// One syncthreads at agg spill; stage 2 from L2.
template<int F_OUT, bool FINAL>
__global__ __launch_bounds__(256, 4)
void gcn_layer(const short* __restrict__ Ahat,    // PT tiled (A+I) bf16
               const float* __restrict__ dinv,
               const short* __restrict__ Gin,     // PT tiled g = d*h, F=256
               const short* __restrict__ WT,      // PT tiled
               const float* __restrict__ bias,
               short* __restrict__ Gout,          // PT tiled, F_OUT
               float* __restrict__ Out) {         // [32][1024][F_OUT] fp32
  __shared__ short aggL[32 * 272];                // 32 r x 544B rows

  int b = blockIdx.x;
  int bw = ((b & 7) << 2) + ((b >> 3) & 3);       // same-XCD blocks share bw
  int rb = b >> 5;                                // 0..31
  int r0 = rb << 5;                               // 32 rows / block

  int tid = threadIdx.x;
  int wid = tid >> 6, lane = tid & 63;
  int l15 = lane & 15, l4 = lane >> 4;            // l4 in 0..3

  const short* Hbase = Gin  + ((size_t)bw << 18) + ((size_t)(wid << 2) << 14) + (lane << 3);
  const short* Abase = Ahat + ((size_t)bw << 20) + ((size_t)(rb << 1) << 14) + (lane << 3);
  const float* dvB = dinv + (bw << 10);
  float dsc0 = dvB[r0 + l15];
  float dsc1 = dvB[r0 + 16 + l15];

  f32x4 acc[4][2];
  #pragma unroll
  for (int am = 0; am < 4; am++)
    #pragma unroll
    for (int nf = 0; nf < 2; nf++) acc[am][nf] = f32x4{0.f, 0.f, 0.f, 0.f};

  bf16x8 he[4], ae[2], ho[4], ao[2];

#define LD(HB, AB, T)                                                         \
  {                                                                           \
    _Pragma("unroll")                                                         \
    for (int am = 0; am < 4; am++)                                            \
      HB[am] = *(const bf16x8*)(Hbase + am * 16384 + (T) * 512);              \
    _Pragma("unroll")                                                         \
    for (int nf = 0; nf < 2; nf++)                                            \
      AB[nf] = *(const bf16x8*)(Abase + nf * 16384 + (T) * 512);              \
  }
#define MM(HB, AB)                                                            \
  _Pragma("unroll")                                                           \
  for (int am = 0; am < 4; am++)                                              \
    _Pragma("unroll")                                                         \
    for (int nf = 0; nf < 2; nf++)                                            \
      acc[am][nf] = __builtin_amdgcn_mfma_f32_16x16x32_bf16(                  \
          HB[am], AB[nf], acc[am][nf], 0, 0, 0);

  LD(he, ae, 0);
  LD(ho, ao, 1);
  #pragma unroll
  for (int it = 0; it < 16; ++it) {
    MM(he, ae);
    if (it < 15) LD(he, ae, 2 * it + 2);
    MM(ho, ao);
    if (it < 15) LD(ho, ao, 2 * it + 3);
  }
#undef LD
#undef MM

  // ---- agg = d[r]*acc -> LDS bf16, XOR-swizzled (byte ^= (r&7)<<4) ----
  #pragma unroll
  for (int am = 0; am < 4; am++)
    #pragma unroll
    for (int nf = 0; nf < 2; nf++) {
      int r = (nf << 4) + l15;
      float ds = nf ? dsc1 : dsc0;
      int fB = ((wid << 6) + (am << 4) + (l4 << 2)) << 1;   // byte col
      int off = (r * 544 + (fB ^ ((r & 7) << 4))) >> 1;
      ushort4 p;
      p.x = (unsigned short)f2bf(acc[am][nf][0] * ds);
      p.y = (unsigned short)f2bf(acc[am][nf][1] * ds);
      p.z = (unsigned short)f2bf(acc[am][nf][2] * ds);
      p.w = (unsigned short)f2bf(acc[am][nf][3] * ds);
      *(ushort4*)(aggL + off) = p;
    }
  __syncthreads();

  // ---- stage 2: out = relu(agg @ W + b), K = 256, W from L2 ----
  constexpr int NFO = F_OUT / 64;
  const short* Wbase = WT + (size_t)(wid * NFO) * 4096 + (lane << 3);
  f32x4 acc2[2][NFO];
  #pragma unroll
  for (int am = 0; am < 2; am++)
    #pragma unroll
    for (int nf = 0; nf < NFO; nf++) acc2[am][nf] = f32x4{0.f, 0.f, 0.f, 0.f};

  #pragma unroll
  for (int kt = 0; kt < 8; kt++) {
    bf16x8 af[2];
    #pragma unroll
    for (int am = 0; am < 2; am++) {
      int r = (am << 4) + l15;
      int fB = (kt << 6) + (l4 << 4);
      af[am] = *(const bf16x8*)(aggL + ((r * 544 + (fB ^ ((r & 7) << 4))) >> 1));
    }
    #pragma unroll
    for (int nf = 0; nf < NFO; nf++) {
      bf16x8 wv = *(const bf16x8*)(Wbase + (size_t)nf * 4096 + (kt << 9));
      #pragma unroll
      for (int am = 0; am < 2; am++)
        acc2[am][nf] = __builtin_amdgcn_mfma_f32_16x16x32_bf16(af[am], wv, acc2[am][nf], 0, 0, 0);
    }
  }

  // ---- epilogue: bias + relu (+d[node] for g-form) + store ----
  #pragma unroll
  for (int am = 0; am < 2; am++) {
    int nodeLoc = (am << 4) + (l4 << 2);          // + j
    float4 dn4 = *(const float4*)(dvB + r0 + nodeLoc);
    float dn[4] = {dn4.x, dn4.y, dn4.z, dn4.w};
    #pragma unroll
    for (int nf = 0; nf < NFO; nf++) {
      int fo = wid * (F_OUT / 4) + (nf << 4) + l15;
      float bb = bias[fo];
      float v[4];
      #pragma unroll
      for (int j = 0; j < 4; j++) v[j] = fmaxf(acc2[am][nf][j] + bb, 0.f);
      if (!FINAL) {
        ushort4 p;
        p.x = (unsigned short)f2bf(v[0] * dn[0]);
        p.y = (unsigned short)f2bf(v[1] * dn[1]);
        p.z = (unsigned short)f2bf(v[2] * dn[2]);
        p.w = (unsigned short)f2bf(v[3] * dn[3]);
        // PT(fo, node): node = r0 + nodeLoc + j
        size_t e = (size_t)bw * (F_OUT * 1024) + ((size_t)(fo >> 4) << 14)
                 + ((size_t)rb << 9) + ((size_t)((am << 1) + (l4 >> 1)) << 7)
                 + ((fo & 15) << 3) + ((l4 & 1) << 2);
        *(ushort4*)(Gout + e) = p;
      } else {
        float* ob = Out + ((size_t)(bw << 10) + r0 + nodeLoc) * F_OUT + fo;
        ob[0]         = v[0];
        ob[F_OUT]     = v[1];
        ob[2 * F_OUT] = v[2];
        ob[3 * F_OUT] = v[3];
      }
    }
  }
}

extern "C" void kernel_launch(void* const* d_in, const int* in_sizes, int n_in,
                              void* d_out, int out_size, void* d_ws, size_t ws_size,
                              hipStream_t stream) {
  const float* X   = (const float*)d_in[0];
  const float* adj = (const float*)d_in[1];
  const float* W1  = (const float*)d_in[2];
  const float* b1  = (const float*)d_in[3];
  const float* W2  = (const float*)d_in[4];
  const float* b2  = (const float*)d_in[5];
  const float* W3  = (const float*)d_in[6];
  const float* b3  = (const float*)d_in[7];
  float* out = (float*)d_out;

  char* ws = (char*)d_ws;
  float* dinv = (float*)ws;                              // 128 KB
  short* WT1  = (short*)(ws + 131072);                   // 128 KB
  short* WT2  = (short*)(ws + 262144);                   // 128 KB
  short* WT3  = (short*)(ws + 393216);                   //  64 KB
  short* bufA = (short*)(ws + 458752);                   //  16 MB
  short* bufB = (short*)(ws + 458752 + 16777216);        //  16 MB
  short* Ahat = (short*)(ws + 458752 + 2 * 16777216);    //  64 MB

  dinv_cast<<<8192, 256, 0, stream>>>(adj, dinv, Ahat);
  transpose_x<<<dim3(16, 4, 32), 256, 0, stream>>>(X, dinv, bufA);
  transpose_w<<<256, 256, 0, stream>>>(W1, WT1, 256);
  transpose_w<<<256, 256, 0, stream>>>(W2, WT2, 256);
  transpose_w<<<128, 256, 0, stream>>>(W3, WT3, 128);

  gcn_layer<256, false><<<1024, 256, 0, stream>>>(Ahat, dinv, bufA, WT1, b1, bufB, nullptr);
  gcn_layer<256, false><<<1024, 256, 0, stream>>>(Ahat, dinv, bufB, WT2, b2, bufA, nullptr);
  gcn_layer<128, true ><<<1024, 256, 0, stream>>>(Ahat, dinv, bufA, WT3, b3, nullptr, out);
}

// Round 6
// 161.330 us; speedup vs baseline: 1.3175x; 1.0992x over previous
//
#include <hip/hip_runtime.h>
#include <hip/hip_bf16.h>
#include <cstdint>
#include <cstddef>

#define NN 1024
#define FF 256

typedef __attribute__((ext_vector_type(8))) short bf16x8;
typedef __attribute__((ext_vector_type(4))) float f32x4;

__device__ __forceinline__ short f2bf(float x) {
  unsigned int u = __float_as_uint(x);
  u = (u + 0x7fffu + ((u >> 16) & 1u)) >> 16;   // RNE
  return (short)u;
}

// ---- PT tiled layout (all bf16 matrices) ----
// 16-row x 32-k tiles (512 elems): elem(row,k) = ((k&31)>>3)*128 + (row&15)*8 + (k&7)
// A wave load at (tile_base + lane*8) IS the MFMA fragment:
//   lane -> (row = lane&15, k = (lane>>4)*8 + j)
// Ahat (1024x1024/bw): bw<<20 + (r>>4)<<14 + (k>>5)<<9 + pt(r,k)
// G    (F x 1024/bw) : bw*F*1024 + (f>>4)<<14 + (n>>5)<<9 + pt(f,n)
// WT   (F_OUT x 256) : (fo>>4)*4096 + (fi>>5)<<9 + pt(fo,fi)

// ---- fused: d = rsqrt(rowsum(adj)+1), Ahat = (adj+I) bf16 PT-tiled ---------
// One block per 16-row stripe; thread t owns PT elems t*8.. -> writes are
// wave-contiguous 1KB; reads are 128B-per-row segments.
__global__ __launch_bounds__(256)
void dinv_cast(const float* __restrict__ adj, float* __restrict__ dinv,
               short* __restrict__ Ahat) {
  __shared__ float wsum[64];
  int b = blockIdx.x;                          // 0..2047 = bw*64 + stripe
  int bw = b >> 6, s = b & 63;
  int t = threadIdx.x;
  int wid = t >> 6, lane = t & 63;
  int row = lane & 15;                         // local row in stripe
  int rloc = (s << 4) + row;                   // row in matrix
  int kg = (lane >> 4) & 3;
  const float* arow = adj + ((size_t)(bw << 10) + rloc) * NN;
  short* outb = Ahat + ((size_t)bw << 20) + ((size_t)s << 14) + (t << 3);
  float ssum = 0.f;
  #pragma unroll
  for (int it = 0; it < 8; it++) {
    int col = (it << 7) + (wid << 5) + (kg << 3);
    float4 a0 = *(const float4*)(arow + col);
    float4 a1 = *(const float4*)(arow + col + 4);
    float v[8] = {a0.x, a0.y, a0.z, a0.w, a1.x, a1.y, a1.z, a1.w};
    union { ushort o[8]; int4 q; } pk;
    #pragma unroll
    for (int j = 0; j < 8; j++) {
      v[j] += (rloc == col + j) ? 1.f : 0.f;
      ssum += v[j];
      pk.o[j] = (ushort)f2bf(v[j]);
    }
    *(int4*)(outb + (it << 11)) = pk.q;
  }
  ssum += __shfl_down(ssum, 32, 64);
  ssum += __shfl_down(ssum, 16, 64);
  if (lane < 16) wsum[(wid << 4) + lane] = ssum;
  __syncthreads();
  if (t < 16) {
    float tot = wsum[t] + wsum[16 + t] + wsum[32 + t] + wsum[48 + t];
    dinv[(bw << 10) + (s << 4) + t] = rsqrtf(tot);
  }
}

// ---- X [bw][n][256] fp32 -> G1 = d[n]*X, PT(f, n) bf16 ---------------------
__global__ __launch_bounds__(256)
void transpose_x(const float* __restrict__ X, const float* __restrict__ dinv,
                 short* __restrict__ XT) {
  __shared__ short T[64][72];
  int bwo = blockIdx.z;
  int n0 = blockIdx.x << 6, f0 = blockIdx.y << 6;
  int t = threadIdx.x;
  {
    int n = t >> 2, fc = (t & 3) << 4;
    float dn = dinv[(bwo << 10) + n0 + n];
    const float* src = X + (((size_t)bwo * NN + n0 + n) * FF) + f0 + fc;
    #pragma unroll
    for (int i = 0; i < 4; i++) {
      float4 v = ((const float4*)src)[i];
      ushort4 p;
      p.x = (unsigned short)f2bf(v.x * dn); p.y = (unsigned short)f2bf(v.y * dn);
      p.z = (unsigned short)f2bf(v.z * dn); p.w = (unsigned short)f2bf(v.w * dn);
      *(ushort4*)&T[n][fc + (i << 2)] = p;
    }
  }
  __syncthreads();
  {
    int f = t >> 2, nc = (t & 3) << 4;
    int fg = f0 + f, ng = n0 + nc;
    short tmp[16];
    #pragma unroll
    for (int i = 0; i < 16; i++) tmp[i] = T[nc + i][f];
    size_t e0 = ((size_t)bwo << 18) + ((size_t)(fg >> 4) << 14) + ((ng >> 5) << 9)
              + (((ng & 31) >> 3) << 7) + ((fg & 15) << 3);
    *(int4*)(XT + e0)       = *(int4*)&tmp[0];
    *(int4*)(XT + e0 + 128) = *(int4*)&tmp[8];
  }
}

// ---- W [256][FO] fp32 -> WT PT(fo, fi) bf16 --------------------------------
__global__ __launch_bounds__(256)
void transpose_w(const float* __restrict__ W, short* __restrict__ WT, int FO) {
  int idx = blockIdx.x * 256 + threadIdx.x;
  if (idx >= FO * 256) return;
  int fo = idx >> 8, fi = idx & 255;
  size_t e = (size_t)((fo >> 4) << 12) + ((fi >> 5) << 9)
           + (((fi & 31) >> 3) << 7) + ((fo & 15) << 3) + (fi & 7);
  WT[e] = f2bf(W[fi * FO + fo]);
}

// ---------------- fused layer ----------------------------------------------
// Grid 512 (32 bw x 16 rb), 512 thr (8 waves = 2 wr x 4 wf), 2 blocks/CU.
// Block tile: 64 rows x 256 f. Wave: 32 r x 64 f. Stage 1 register-only,
// depth-2 pipeline, no barriers. One syncthreads at agg spill; stage 2 from L2.
template<int F_OUT, bool FINAL>
__global__ __launch_bounds__(512, 4)
void gcn_layer(const short* __restrict__ Ahat,    // PT tiled (A+I) bf16
               const float* __restrict__ dinv,
               const short* __restrict__ Gin,     // PT tiled g = d*h, F=256
               const short* __restrict__ WT,      // PT tiled
               const float* __restrict__ bias,
               short* __restrict__ Gout,          // PT tiled, F_OUT
               float* __restrict__ Out) {         // [32][1024][F_OUT] fp32
  __shared__ short aggL[64 * 272];                // 64 r x 544B rows

  int b = blockIdx.x;
  int bw = ((b & 7) << 2) + ((b >> 3) & 3);       // same-XCD blocks share bw
  int rb = b >> 5;                                // 0..15
  int r0 = rb << 6;                               // 64 rows / block

  int tid = threadIdx.x;
  int wid = tid >> 6, lane = tid & 63;
  int l15 = lane & 15, l4 = lane >> 4;            // l4 in 0..3
  int wr = wid >> 2, wf = wid & 3;

  const short* Hbase = Gin  + ((size_t)bw << 18) + ((size_t)(wf << 2) << 14) + (lane << 3);
  const short* Abase = Ahat + ((size_t)bw << 20)
                     + ((size_t)((rb << 2) + (wr << 1)) << 14) + (lane << 3);
  const float* dvB = dinv + (bw << 10);
  float dsc0 = dvB[r0 + (wr << 5) + l15];
  float dsc1 = dvB[r0 + (wr << 5) + 16 + l15];

  f32x4 acc[4][2];
  #pragma unroll
  for (int am = 0; am < 4; am++)
    #pragma unroll
    for (int nf = 0; nf < 2; nf++) acc[am][nf] = f32x4{0.f, 0.f, 0.f, 0.f};

  bf16x8 he[4], ae[2], ho[4], ao[2];

#define LD(HB, AB, T)                                                         \
  {                                                                           \
    _Pragma("unroll")                                                         \
    for (int am = 0; am < 4; am++)                                            \
      HB[am] = *(const bf16x8*)(Hbase + am * 16384 + (T) * 512);              \
    _Pragma("unroll")                                                         \
    for (int nf = 0; nf < 2; nf++)                                            \
      AB[nf] = *(const bf16x8*)(Abase + nf * 16384 + (T) * 512);              \
  }
#define MM(HB, AB)                                                            \
  _Pragma("unroll")                                                           \
  for (int am = 0; am < 4; am++)                                              \
    _Pragma("unroll")                                                         \
    for (int nf = 0; nf < 2; nf++)                                            \
      acc[am][nf] = __builtin_amdgcn_mfma_f32_16x16x32_bf16(                  \
          HB[am], AB[nf], acc[am][nf], 0, 0, 0);

  LD(he, ae, 0);
  LD(ho, ao, 1);
  #pragma unroll
  for (int it = 0; it < 16; ++it) {
    MM(he, ae);
    if (it < 15) LD(he, ae, 2 * it + 2);
    MM(ho, ao);
    if (it < 15) LD(ho, ao, 2 * it + 3);
  }
#undef LD
#undef MM

  // ---- agg = d[r]*acc -> LDS bf16, XOR-swizzled (byte ^= (r&7)<<4) ----
  #pragma unroll
  for (int am = 0; am < 4; am++)
    #pragma unroll
    for (int nf = 0; nf < 2; nf++) {
      int r = (wr << 5) + (nf << 4) + l15;
      float ds = nf ? dsc1 : dsc0;
      int fB = ((wf << 6) + (am << 4) + (l4 << 2)) << 1;   // byte col
      int off = (r * 544 + (fB ^ ((r & 7) << 4))) >> 1;
      ushort4 p;
      p.x = (unsigned short)f2bf(acc[am][nf][0] * ds);
      p.y = (unsigned short)f2bf(acc[am][nf][1] * ds);
      p.z = (unsigned short)f2bf(acc[am][nf][2] * ds);
      p.w = (unsigned short)f2bf(acc[am][nf][3] * ds);
      *(ushort4*)(aggL + off) = p;
    }
  __syncthreads();

  // ---- stage 2: out = relu(agg @ W + b), K = 256, W from L2 ----
  constexpr int NFO = F_OUT / 64;                 // fo-tiles per wave
  const short* Wbase = WT + (size_t)(wf * NFO) * 4096 + (lane << 3);
  f32x4 acc2[2][NFO];
  #pragma unroll
  for (int am = 0; am < 2; am++)
    #pragma unroll
    for (int nf = 0; nf < NFO; nf++) acc2[am][nf] = f32x4{0.f, 0.f, 0.f, 0.f};

  #pragma unroll
  for (int kt = 0; kt < 8; kt++) {
    bf16x8 af[2];
    #pragma unroll
    for (int am = 0; am < 2; am++) {
      int r = (wr << 5) + (am << 4) + l15;
      int fB = (kt << 6) + (l4 << 4);
      af[am] = *(const bf16x8*)(aggL + ((r * 544 + (fB ^ ((r & 7) << 4))) >> 1));
    }
    #pragma unroll
    for (int nf = 0; nf < NFO; nf++) {
      bf16x8 wv = *(const bf16x8*)(Wbase + (size_t)nf * 4096 + (kt << 9));
      #pragma unroll
      for (int am = 0; am < 2; am++)
        acc2[am][nf] = __builtin_amdgcn_mfma_f32_16x16x32_bf16(af[am], wv, acc2[am][nf], 0, 0, 0);
    }
  }

  // ---- epilogue: bias + relu (+d[node] for g-form) + store ----
  #pragma unroll
  for (int am = 0; am < 2; am++) {
    int nodeLoc = (wr << 5) + (am << 4) + (l4 << 2);      // + j
    float4 dn4 = *(const float4*)(dvB + r0 + nodeLoc);
    float dn[4] = {dn4.x, dn4.y, dn4.z, dn4.w};
    #pragma unroll
    for (int nf = 0; nf < NFO; nf++) {
      int fo = wf * (F_OUT / 4) + (nf << 4) + l15;
      float bb = bias[fo];
      float v[4];
      #pragma unroll
      for (int j = 0; j < 4; j++) v[j] = fmaxf(acc2[am][nf][j] + bb, 0.f);
      if (!FINAL) {
        ushort4 p;
        p.x = (unsigned short)f2bf(v[0] * dn[0]);
        p.y = (unsigned short)f2bf(v[1] * dn[1]);
        p.z = (unsigned short)f2bf(v[2] * dn[2]);
        p.w = (unsigned short)f2bf(v[3] * dn[3]);
        size_t e = (size_t)bw * (F_OUT * 1024) + ((size_t)(fo >> 4) << 14)
                 + ((size_t)((rb << 1) + wr) << 9)
                 + ((size_t)((am << 1) + (l4 >> 1)) << 7)
                 + ((fo & 15) << 3) + ((l4 & 1) << 2);
        *(ushort4*)(Gout + e) = p;
      } else {
        float* ob = Out + ((size_t)(bw << 10) + r0 + nodeLoc) * F_OUT + fo;
        ob[0]         = v[0];
        ob[F_OUT]     = v[1];
        ob[2 * F_OUT] = v[2];
        ob[3 * F_OUT] = v[3];
      }
    }
  }
}

extern "C" void kernel_launch(void* const* d_in, const int* in_sizes, int n_in,
                              void* d_out, int out_size, void* d_ws, size_t ws_size,
                              hipStream_t stream) {
  const float* X   = (const float*)d_in[0];
  const float* adj = (const float*)d_in[1];
  const float* W1  = (const float*)d_in[2];
  const float* b1  = (const float*)d_in[3];
  const float* W2  = (const float*)d_in[4];
  const float* b2  = (const float*)d_in[5];
  const float* W3  = (const float*)d_in[6];
  const float* b3  = (const float*)d_in[7];
  float* out = (float*)d_out;

  char* ws = (char*)d_ws;
  float* dinv = (float*)ws;                              // 128 KB
  short* WT1  = (short*)(ws + 131072);                   // 128 KB
  short* WT2  = (short*)(ws + 262144);                   // 128 KB
  short* WT3  = (short*)(ws + 393216);                   //  64 KB
  short* bufA = (short*)(ws + 458752);                   //  16 MB
  short* bufB = (short*)(ws + 458752 + 16777216);        //  16 MB
  short* Ahat = (short*)(ws + 458752 + 2 * 16777216);    //  64 MB

  dinv_cast<<<2048, 256, 0, stream>>>(adj, dinv, Ahat);
  transpose_x<<<dim3(16, 4, 32), 256, 0, stream>>>(X, dinv, bufA);
  transpose_w<<<256, 256, 0, stream>>>(W1, WT1, 256);
  transpose_w<<<256, 256, 0, stream>>>(W2, WT2, 256);
  transpose_w<<<128, 256, 0, stream>>>(W3, WT3, 128);

  gcn_layer<256, false><<<512, 512, 0, stream>>>(Ahat, dinv, bufA, WT1, b1, bufB, nullptr);
  gcn_layer<256, false><<<512, 512, 0, stream>>>(Ahat, dinv, bufB, WT2, b2, bufA, nullptr);
  gcn_layer<128, true ><<<512, 512, 0, stream>>>(Ahat, dinv, bufA, WT3, b3, nullptr, out);
}

// Round 7
// 138.936 us; speedup vs baseline: 1.5299x; 1.1612x over previous
//
#include <hip/hip_runtime.h>
#include <hip/hip_bf16.h>
#include <cstdint>
#include <cstddef>

#define NN 1024
#define FF 256

typedef __attribute__((ext_vector_type(8))) short bf16x8;
typedef __attribute__((ext_vector_type(4))) float f32x4;

__device__ __forceinline__ short f2bf(float x) {
  unsigned int u = __float_as_uint(x);
  u = (u + 0x7fffu + ((u >> 16) & 1u)) >> 16;   // RNE
  return (short)u;
}

// ---- PT tiled layout (all bf16 matrices) ----
// 16-row x 32-k tiles (512 elems): elem(row,k) = ((k&31)>>3)*128 + (row&15)*8 + (k&7)
// A wave load at (tile_base + lane*8) IS the MFMA fragment:
//   lane -> (row = lane&15, k = (lane>>4)*8 + j)
// Ahat (1024x1024/bw): bw<<20 + (r>>4)<<14 + (k>>5)<<9 + pt(r,k)
// G    (F x 1024/bw) : bw*F*1024 + (f>>4)<<14 + (n>>5)<<9 + pt(f,n)
// WT   (F_OUT x 256) : (fo>>4)*4096 + (fi>>5)<<9 + pt(fo,fi)

// ---- fused: d = rsqrt(rowsum(adj)+1), Ahat = (adj+I) bf16 PT-tiled ---------
__global__ __launch_bounds__(256)
void dinv_cast(const float* __restrict__ adj, float* __restrict__ dinv,
               short* __restrict__ Ahat) {
  __shared__ float wsum[64];
  int b = blockIdx.x;                          // 0..2047 = bw*64 + stripe
  int bw = b >> 6, s = b & 63;
  int t = threadIdx.x;
  int wid = t >> 6, lane = t & 63;
  int row = lane & 15;                         // local row in stripe
  int rloc = (s << 4) + row;                   // row in matrix
  int kg = (lane >> 4) & 3;
  const float* arow = adj + ((size_t)(bw << 10) + rloc) * NN;
  short* outb = Ahat + ((size_t)bw << 20) + ((size_t)s << 14) + (t << 3);
  float ssum = 0.f;
  #pragma unroll
  for (int it = 0; it < 8; it++) {
    int col = (it << 7) + (wid << 5) + (kg << 3);
    float4 a0 = *(const float4*)(arow + col);
    float4 a1 = *(const float4*)(arow + col + 4);
    float v[8] = {a0.x, a0.y, a0.z, a0.w, a1.x, a1.y, a1.z, a1.w};
    union { ushort o[8]; int4 q; } pk;
    #pragma unroll
    for (int j = 0; j < 8; j++) {
      v[j] += (rloc == col + j) ? 1.f : 0.f;
      ssum += v[j];
      pk.o[j] = (ushort)f2bf(v[j]);
    }
    *(int4*)(outb + (it << 11)) = pk.q;
  }
  ssum += __shfl_down(ssum, 32, 64);
  ssum += __shfl_down(ssum, 16, 64);
  if (lane < 16) wsum[(wid << 4) + lane] = ssum;
  __syncthreads();
  if (t < 16) {
    float tot = wsum[t] + wsum[16 + t] + wsum[32 + t] + wsum[48 + t];
    dinv[(bw << 10) + (s << 4) + t] = rsqrtf(tot);
  }
}

// ---- X [bw][n][256] fp32 -> G1 = d[n]*X, PT(f, n) bf16 ---------------------
__global__ __launch_bounds__(256)
void transpose_x(const float* __restrict__ X, const float* __restrict__ dinv,
                 short* __restrict__ XT) {
  __shared__ short T[64][72];
  int bwo = blockIdx.z;
  int n0 = blockIdx.x << 6, f0 = blockIdx.y << 6;
  int t = threadIdx.x;
  {
    int n = t >> 2, fc = (t & 3) << 4;
    float dn = dinv[(bwo << 10) + n0 + n];
    const float* src = X + (((size_t)bwo * NN + n0 + n) * FF) + f0 + fc;
    #pragma unroll
    for (int i = 0; i < 4; i++) {
      float4 v = ((const float4*)src)[i];
      ushort4 p;
      p.x = (unsigned short)f2bf(v.x * dn); p.y = (unsigned short)f2bf(v.y * dn);
      p.z = (unsigned short)f2bf(v.z * dn); p.w = (unsigned short)f2bf(v.w * dn);
      *(ushort4*)&T[n][fc + (i << 2)] = p;
    }
  }
  __syncthreads();
  {
    int f = t >> 2, nc = (t & 3) << 4;
    int fg = f0 + f, ng = n0 + nc;
    short tmp[16];
    #pragma unroll
    for (int i = 0; i < 16; i++) tmp[i] = T[nc + i][f];
    size_t e0 = ((size_t)bwo << 18) + ((size_t)(fg >> 4) << 14) + ((ng >> 5) << 9)
              + (((ng & 31) >> 3) << 7) + ((fg & 15) << 3);
    *(int4*)(XT + e0)       = *(int4*)&tmp[0];
    *(int4*)(XT + e0 + 128) = *(int4*)&tmp[8];
  }
}

// ---- W [256][FO] fp32 -> WT PT(fo, fi) bf16 --------------------------------
__global__ __launch_bounds__(256)
void transpose_w(const float* __restrict__ W, short* __restrict__ WT, int FO) {
  int idx = blockIdx.x * 256 + threadIdx.x;
  if (idx >= FO * 256) return;
  int fo = idx >> 8, fi = idx & 255;
  size_t e = (size_t)((fo >> 4) << 12) + ((fi >> 5) << 9)
           + (((fi & 31) >> 3) << 7) + ((fo & 15) << 3) + (fi & 7);
  WT[e] = f2bf(W[fi * FO + fo]);
}

// ---------------- fused layer ----------------------------------------------
// Grid 512 (8 XCD x 4 bw x 16 rb), 256 thr (4 waves), 3 blocks/CU.
// Block tile: 64 r x 256 f; wave tile 64 r x 64 f (4x4 fragment blocking:
// 16 MFMA per 8KB fetched = 512 B/MFMA). Co-resident blocks share bw ->
// A/G fragment duplication served by L1. Stage 1 register-only, no barriers.
template<int F_OUT, bool FINAL>
__global__ __launch_bounds__(256, 3)
void gcn_layer(const short* __restrict__ Ahat,    // PT tiled (A+I) bf16
               const float* __restrict__ dinv,
               const short* __restrict__ Gin,     // PT tiled g = d*h, F=256
               const short* __restrict__ WT,      // PT tiled
               const float* __restrict__ bias,
               short* __restrict__ Gout,          // PT tiled, F_OUT
               float* __restrict__ Out) {         // [32][1024][F_OUT] fp32
  __shared__ short aggL[64 * 272];                // 64 r x 544B rows

  int b = blockIdx.x;
  int x = b & 7, m = b >> 3;
  int bw = (x << 2) + (m >> 4);                   // same-XCD neighbors: same bw
  int rb = m & 15;
  int r0 = rb << 6;                               // 64 rows / block

  int tid = threadIdx.x;
  int wf = tid >> 6, lane = tid & 63;
  int l15 = lane & 15, l4 = lane >> 4;            // l4 in 0..3

  const short* Hbase = Gin  + ((size_t)bw << 18) + ((size_t)(wf << 2) << 14) + (lane << 3);
  const short* Abase = Ahat + ((size_t)bw << 20) + ((size_t)(rb << 2) << 14) + (lane << 3);
  const float* dvB = dinv + (bw << 10);

  f32x4 acc[4][4];                                // [ah(f)][aa(r)]
  #pragma unroll
  for (int ah = 0; ah < 4; ah++)
    #pragma unroll
    for (int aa = 0; aa < 4; aa++) acc[ah][aa] = f32x4{0.f, 0.f, 0.f, 0.f};

  bf16x8 hE[4], aE[4], hO[4], aO[4];

#define LD(HB, AB, T)                                                         \
  {                                                                           \
    _Pragma("unroll")                                                         \
    for (int ah = 0; ah < 4; ah++)                                            \
      HB[ah] = *(const bf16x8*)(Hbase + ah * 16384 + (T) * 512);              \
    _Pragma("unroll")                                                         \
    for (int aa = 0; aa < 4; aa++)                                            \
      AB[aa] = *(const bf16x8*)(Abase + aa * 16384 + (T) * 512);              \
  }
#define MM(HB, AB)                                                            \
  __builtin_amdgcn_s_setprio(1);                                              \
  _Pragma("unroll")                                                           \
  for (int ah = 0; ah < 4; ah++)                                              \
    _Pragma("unroll")                                                         \
    for (int aa = 0; aa < 4; aa++)                                            \
      acc[ah][aa] = __builtin_amdgcn_mfma_f32_16x16x32_bf16(                  \
          HB[ah], AB[aa], acc[ah][aa], 0, 0, 0);                              \
  __builtin_amdgcn_s_setprio(0);

  LD(hE, aE, 0);
  LD(hO, aO, 1);
  #pragma unroll
  for (int it = 0; it < 16; ++it) {
    MM(hE, aE);
    if (it < 15) LD(hE, aE, 2 * it + 2);
    MM(hO, aO);
    if (it < 15) LD(hO, aO, 2 * it + 3);
  }
#undef LD
#undef MM

  // ---- agg = d[r]*acc -> LDS bf16, XOR-swizzled (byte ^= (r&7)<<4) ----
  float dsc[4];
  #pragma unroll
  for (int aa = 0; aa < 4; aa++) dsc[aa] = dvB[r0 + (aa << 4) + l15];
  #pragma unroll
  for (int ah = 0; ah < 4; ah++)
    #pragma unroll
    for (int aa = 0; aa < 4; aa++) {
      int r = (aa << 4) + l15;
      int fB = ((wf << 6) + (ah << 4) + (l4 << 2)) << 1;   // byte col
      int off = (r * 544 + (fB ^ ((r & 7) << 4))) >> 1;
      ushort4 p;
      p.x = (unsigned short)f2bf(acc[ah][aa][0] * dsc[aa]);
      p.y = (unsigned short)f2bf(acc[ah][aa][1] * dsc[aa]);
      p.z = (unsigned short)f2bf(acc[ah][aa][2] * dsc[aa]);
      p.w = (unsigned short)f2bf(acc[ah][aa][3] * dsc[aa]);
      *(ushort4*)(aggL + off) = p;
    }
  __syncthreads();

  // ---- stage 2: out = relu(agg @ W + b), K = 256, W from L2 ----
  constexpr int NFO = F_OUT / 64;                 // fo-tiles per wave
  const short* Wbase = WT + (size_t)(wf * NFO) * 4096 + (lane << 3);
  f32x4 acc2[4][NFO];
  #pragma unroll
  for (int am = 0; am < 4; am++)
    #pragma unroll
    for (int nf = 0; nf < NFO; nf++) acc2[am][nf] = f32x4{0.f, 0.f, 0.f, 0.f};

  #pragma unroll
  for (int kt = 0; kt < 8; kt++) {
    bf16x8 af[4];
    #pragma unroll
    for (int am = 0; am < 4; am++) {
      int r = (am << 4) + l15;
      int fB = (kt << 6) + (l4 << 4);
      af[am] = *(const bf16x8*)(aggL + ((r * 544 + (fB ^ ((r & 7) << 4))) >> 1));
    }
    #pragma unroll
    for (int nf = 0; nf < NFO; nf++) {
      bf16x8 wv = *(const bf16x8*)(Wbase + (size_t)nf * 4096 + (kt << 9));
      #pragma unroll
      for (int am = 0; am < 4; am++)
        acc2[am][nf] = __builtin_amdgcn_mfma_f32_16x16x32_bf16(af[am], wv, acc2[am][nf], 0, 0, 0);
    }
  }

  // ---- epilogue: bias + relu (+d[node] for g-form) + store ----
  #pragma unroll
  for (int am = 0; am < 4; am++) {
    int nodeLoc = (am << 4) + (l4 << 2);          // + j
    float4 dn4 = *(const float4*)(dvB + r0 + nodeLoc);
    float dn[4] = {dn4.x, dn4.y, dn4.z, dn4.w};
    #pragma unroll
    for (int nf = 0; nf < NFO; nf++) {
      int fo = wf * (F_OUT / 4) + (nf << 4) + l15;
      float bb = bias[fo];
      float v[4];
      #pragma unroll
      for (int j = 0; j < 4; j++) v[j] = fmaxf(acc2[am][nf][j] + bb, 0.f);
      if (!FINAL) {
        ushort4 p;
        p.x = (unsigned short)f2bf(v[0] * dn[0]);
        p.y = (unsigned short)f2bf(v[1] * dn[1]);
        p.z = (unsigned short)f2bf(v[2] * dn[2]);
        p.w = (unsigned short)f2bf(v[3] * dn[3]);
        size_t e = (size_t)bw * (F_OUT * 1024) + ((size_t)(fo >> 4) << 14)
                 + ((size_t)((rb << 1) + (am >> 1)) << 9)
                 + ((size_t)(((am & 1) << 1) + (l4 >> 1)) << 7)
                 + ((fo & 15) << 3) + ((l4 & 1) << 2);
        *(ushort4*)(Gout + e) = p;
      } else {
        float* ob = Out + ((size_t)(bw << 10) + r0 + nodeLoc) * F_OUT + fo;
        ob[0]         = v[0];
        ob[F_OUT]     = v[1];
        ob[2 * F_OUT] = v[2];
        ob[3 * F_OUT] = v[3];
      }
    }
  }
}

extern "C" void kernel_launch(void* const* d_in, const int* in_sizes, int n_in,
                              void* d_out, int out_size, void* d_ws, size_t ws_size,
                              hipStream_t stream) {
  const float* X   = (const float*)d_in[0];
  const float* adj = (const float*)d_in[1];
  const float* W1  = (const float*)d_in[2];
  const float* b1  = (const float*)d_in[3];
  const float* W2  = (const float*)d_in[4];
  const float* b2  = (const float*)d_in[5];
  const float* W3  = (const float*)d_in[6];
  const float* b3  = (const float*)d_in[7];
  float* out = (float*)d_out;

  char* ws = (char*)d_ws;
  float* dinv = (float*)ws;                              // 128 KB
  short* WT1  = (short*)(ws + 131072);                   // 128 KB
  short* WT2  = (short*)(ws + 262144);                   // 128 KB
  short* WT3  = (short*)(ws + 393216);                   //  64 KB
  short* bufA = (short*)(ws + 458752);                   //  16 MB
  short* bufB = (short*)(ws + 458752 + 16777216);        //  16 MB
  short* Ahat = (short*)(ws + 458752 + 2 * 16777216);    //  64 MB

  dinv_cast<<<2048, 256, 0, stream>>>(adj, dinv, Ahat);
  transpose_x<<<dim3(16, 4, 32), 256, 0, stream>>>(X, dinv, bufA);
  transpose_w<<<256, 256, 0, stream>>>(W1, WT1, 256);
  transpose_w<<<256, 256, 0, stream>>>(W2, WT2, 256);
  transpose_w<<<128, 256, 0, stream>>>(W3, WT3, 128);

  gcn_layer<256, false><<<512, 256, 0, stream>>>(Ahat, dinv, bufA, WT1, b1, bufB, nullptr);
  gcn_layer<256, false><<<512, 256, 0, stream>>>(Ahat, dinv, bufB, WT2, b2, bufA, nullptr);
  gcn_layer<128, true ><<<512, 256, 0, stream>>>(Ahat, dinv, bufA, WT3, b3, nullptr, out);
}